// Round 1
// baseline (553.861 us; speedup 1.0000x reference)
//
#include <hip/hip_runtime.h>
#include <hip/hip_bf16.h>

#define B_  4
#define L_  6400
#define C_  768
#define NH_ 6
#define NP_ 4
#define DH_ 128
#define HW_ 80
#define M_  (B_*L_)   // 25600

using f32x4  = float __attribute__((ext_vector_type(4)));
using bf16x8 = short __attribute__((ext_vector_type(8)));

__device__ __forceinline__ ushort f2bf(float f) {
    __hip_bfloat16 h = __float2bfloat16(f);
    return *reinterpret_cast<ushort*>(&h);
}
__device__ __forceinline__ float bf2f(ushort u) {
    union { unsigned u; float f; } v; v.u = ((unsigned)u) << 16; return v.f;
}

// ---------------- K0: weight prep (transpose + bf16 cast, pad Wcomb to 128 cols)
__global__ __launch_bounds__(256) void prep_weights(
    const float* __restrict__ Wv, const float* __restrict__ Woff,
    const float* __restrict__ Waw, const float* __restrict__ boff,
    const float* __restrict__ baw, const float* __restrict__ Wout,
    ushort* __restrict__ Wv_t, ushort* __restrict__ Wout_t,
    ushort* __restrict__ Wcomb_t, float* __restrict__ comb_bias)
{
    int i = blockIdx.x * 256 + threadIdx.x;
    const int WSZ = C_ * C_;              // 589824
    if (i < WSZ) {
        int n = i / C_, k = i % C_;
        Wv_t[i]   = f2bf(Wv[k * C_ + n]);
        Wout_t[i] = f2bf(Wout[k * C_ + n]);
    } else {
        int j = i - WSZ;
        if (j < 128 * C_) {
            int n = j / C_, k = j % C_;
            float v = 0.f;
            if (n < 48)      v = Woff[k * 48 + n];
            else if (n < 72) v = Waw[k * 24 + (n - 48)];
            Wcomb_t[j] = f2bf(v);
        }
    }
    if (i < 128) {
        float v = 0.f;
        if (i < 48)      v = boff[i];
        else if (i < 72) v = baw[i - 48];
        comb_bias[i] = v;
    }
}

// ---------------- K1: LayerNorm for q (from x) and fnorm (from feat), bf16 out
__global__ __launch_bounds__(256) void ln_kernel(
    const float* __restrict__ x, const float* __restrict__ feat,
    const float* __restrict__ qw, const float* __restrict__ qb,
    const float* __restrict__ fw, const float* __restrict__ fb,
    ushort* __restrict__ q, ushort* __restrict__ fn)
{
    int wave = threadIdx.x >> 6, lane = threadIdx.x & 63;
    long r = (long)blockIdx.x * 4 + wave;          // 0 .. 2*M_-1
    const float* in; ushort* out; const float* w; const float* b;
    if (r < M_) { in = x + r * C_;          out = q  + r * C_;          w = qw; b = qb; }
    else        { long rr = r - M_; in = feat + rr * C_; out = fn + rr * C_; w = fw; b = fb; }

    const float4* in4 = (const float4*)in;
    float4 v[3];
    float s = 0.f, s2 = 0.f;
#pragma unroll
    for (int i = 0; i < 3; i++) {
        v[i] = in4[lane + 64 * i];
        s  += v[i].x + v[i].y + v[i].z + v[i].w;
        s2 += v[i].x*v[i].x + v[i].y*v[i].y + v[i].z*v[i].z + v[i].w*v[i].w;
    }
#pragma unroll
    for (int off = 32; off; off >>= 1) { s += __shfl_xor(s, off); s2 += __shfl_xor(s2, off); }
    float mean = s * (1.f / C_);
    float var  = s2 * (1.f / C_) - mean * mean;
    float rs   = rsqrtf(var + 1e-6f);
#pragma unroll
    for (int i = 0; i < 3; i++) {
        int c = (lane + 64 * i) * 4;
        ushort4 o;
        o.x = f2bf((v[i].x - mean) * rs * w[c + 0] + b[c + 0]);
        o.y = f2bf((v[i].y - mean) * rs * w[c + 1] + b[c + 1]);
        o.z = f2bf((v[i].z - mean) * rs * w[c + 2] + b[c + 2]);
        o.w = f2bf((v[i].w - mean) * rs * w[c + 3] + b[c + 3]);
        ((ushort4*)out)[lane + 64 * i] = o;
    }
}

// ---------------- GEMM: C[M,N] = A[M,K] * Bt[N,K]^T + bias, K=768
// MODE 0: store bf16 (value). MODE 1: store f32, ldc stride (scores).
// MODE 2: out = xres + gamma * (acc + bias), f32 (final).
template<int MODE>
__global__ __launch_bounds__(256) void gemm_bf16(
    const ushort* __restrict__ A, const ushort* __restrict__ Bt,
    const float* __restrict__ bias, void* __restrict__ Cout,
    const float* __restrict__ xres, const float* __restrict__ gamma,
    int ldc)
{
    const int K = C_;
    __shared__ ushort As[64][40];   // stride 40 elems = 80 B (16B-aligned rows)
    __shared__ ushort Bs[64][40];
    int m0 = blockIdx.y * 64;
    int n0 = blockIdx.x * 64;
    int tid  = threadIdx.x;
    int wid  = tid >> 6, lane = tid & 63;
    int wr = (wid >> 1) * 32, wc = (wid & 1) * 32;
    f32x4 acc[2][2] = {};
    int sr = tid >> 2;            // staging row 0..63
    int sk = (tid & 3) * 8;       // staging k-chunk
    const int row15 = lane & 15, kb = (lane >> 4) * 8;

    for (int k0 = 0; k0 < K; k0 += 32) {
        __syncthreads();
        *(bf16x8*)&As[sr][sk] = *(const bf16x8*)&A[(long)(m0 + sr) * K + k0 + sk];
        *(bf16x8*)&Bs[sr][sk] = *(const bf16x8*)&Bt[(long)(n0 + sr) * K + k0 + sk];
        __syncthreads();
        bf16x8 af[2], bfr[2];
        af[0]  = *(bf16x8*)&As[wr +      row15][kb];
        af[1]  = *(bf16x8*)&As[wr + 16 + row15][kb];
        bfr[0] = *(bf16x8*)&Bs[wc +      row15][kb];
        bfr[1] = *(bf16x8*)&Bs[wc + 16 + row15][kb];
#pragma unroll
        for (int m = 0; m < 2; m++)
#pragma unroll
            for (int n = 0; n < 2; n++)
                acc[m][n] = __builtin_amdgcn_mfma_f32_16x16x32_bf16(af[m], bfr[n], acc[m][n], 0, 0, 0);
    }

    int rbase = (lane >> 4) * 4;
    int cbase = lane & 15;
#pragma unroll
    for (int m = 0; m < 2; m++)
#pragma unroll
    for (int n = 0; n < 2; n++) {
        int gcol = n0 + wc + n * 16 + cbase;
        float bb = bias[gcol];
#pragma unroll
        for (int j = 0; j < 4; j++) {
            int grow = m0 + wr + m * 16 + rbase + j;
            float vv = acc[m][n][j] + bb;
            if (MODE == 0) {
                ((ushort*)Cout)[(long)grow * C_ + gcol] = f2bf(vv);
            } else if (MODE == 1) {
                ((float*)Cout)[(long)grow * ldc + gcol] = vv;
            } else {
                long o = (long)grow * C_ + gcol;
                ((float*)Cout)[o] = xres[o] + gamma[gcol] * vv;
            }
        }
    }
}

// ---------------- K3: per-row softmax over NP=4 per head + sampling locations
__global__ __launch_bounds__(256) void loc_kernel(
    const float* __restrict__ scores,   // [M][128]: 0..47 offs, 48..71 aw logits
    const float* __restrict__ refp,     // [B,L,1,2]
    float4* __restrict__ samp)          // [M][NH*NP] = {lx, ly, w, 0}
{
    int wave = threadIdx.x >> 6, lane = threadIdx.x & 63;
    long row = (long)blockIdx.x * 4 + wave;
    if (lane >= 24) return;
    const float* sc = scores + row * 128;
    int h = lane >> 2, p = lane & 3;
    float ox = sc[h * 8 + p * 2], oy = sc[h * 8 + p * 2 + 1];
    float logit = sc[48 + lane];
    float m = logit;
    m = fmaxf(m, __shfl_xor(m, 1));
    m = fmaxf(m, __shfl_xor(m, 2));
    float e = expf(logit - m);
    float ssum = e;
    ssum += __shfl_xor(ssum, 1);
    ssum += __shfl_xor(ssum, 2);
    float w = e / ssum;
    float rx = refp[row * 2], ry = refp[row * 2 + 1];
    samp[row * 24 + lane] = make_float4(rx * HW_ + ox - 0.5f, ry * HW_ + oy - 0.5f, w, 0.f);
}

// ---------------- K4: bilinear gather + weighted sum -> attn_out (bf16)
__global__ __launch_bounds__(256) void sample_kernel(
    const ushort* __restrict__ value,   // [B,L,NH,DH] bf16
    const float4* __restrict__ samp,    // [M][24]
    ushort* __restrict__ attn_out)      // [M][C] bf16
{
    int wave = threadIdx.x >> 6, lane = threadIdx.x & 63;
    long gid = (long)blockIdx.x * 4 + wave;     // (b*L + l)*NH + h
    long bl = gid / NH_; int h = (int)(gid % NH_);
    long b = bl / L_;
    long base = (b * (long)L_ * NH_ + h) * DH_ + lane * 2;
    const float4* sp = samp + bl * 24 + h * 4;
    float acc0 = 0.f, acc1 = 0.f;
#pragma unroll
    for (int p = 0; p < 4; p++) {
        float4 s = sp[p];
        float lx = s.x, ly = s.y, wgt = s.z;
        float x0f = floorf(lx), y0f = floorf(ly);
        float tx = lx - x0f, ty = ly - y0f;
        int x0 = (int)x0f, y0 = (int)y0f;
#pragma unroll
        for (int dy = 0; dy < 2; dy++) {
            int yi = y0 + dy;
            if (yi < 0 || yi >= HW_) continue;
            float wy = dy ? ty : 1.f - ty;
#pragma unroll
            for (int dx = 0; dx < 2; dx++) {
                int xi = x0 + dx;
                if (xi < 0 || xi >= HW_) continue;
                float wx = dx ? tx : 1.f - tx;
                float wcr = wgt * wy * wx;
                unsigned v = *(const unsigned*)(value + base + (long)(yi * HW_ + xi) * (NH_ * DH_));
                acc0 += wcr * bf2f((ushort)(v & 0xffffu));
                acc1 += wcr * bf2f((ushort)(v >> 16));
            }
        }
    }
    unsigned o = ((unsigned)f2bf(acc1) << 16) | (unsigned)f2bf(acc0);
    *(unsigned*)(attn_out + gid * DH_ + lane * 2) = o;
}

extern "C" void kernel_launch(void* const* d_in, const int* in_sizes, int n_in,
                              void* d_out, int out_size, void* d_ws, size_t ws_size,
                              hipStream_t stream) {
    const float* x     = (const float*)d_in[0];
    const float* refp  = (const float*)d_in[1];
    const float* feat  = (const float*)d_in[2];
    const float* qn_w  = (const float*)d_in[5];
    const float* qn_b  = (const float*)d_in[6];
    const float* fn_w  = (const float*)d_in[7];
    const float* fn_b  = (const float*)d_in[8];
    const float* gamma = (const float*)d_in[9];
    const float* Wv    = (const float*)d_in[10];
    const float* bv    = (const float*)d_in[11];
    const float* Woff  = (const float*)d_in[12];
    const float* boff  = (const float*)d_in[13];
    const float* Waw   = (const float*)d_in[14];
    const float* baw   = (const float*)d_in[15];
    const float* Wout  = (const float*)d_in[16];
    const float* bout  = (const float*)d_in[17];

    char* ws = (char*)d_ws;
    size_t off = 0;
    auto alloc = [&](size_t bytes) -> void* {
        void* p = ws + off; off += (bytes + 255) & ~(size_t)255; return p;
    };
    ushort* q       = (ushort*)alloc((size_t)M_ * C_ * 2);
    ushort* fn      = (ushort*)alloc((size_t)M_ * C_ * 2);
    ushort* value   = (ushort*)alloc((size_t)M_ * C_ * 2);
    float4* samp    = (float4*)alloc((size_t)M_ * 24 * 16);
    ushort* Wv_t    = (ushort*)alloc((size_t)C_ * C_ * 2);
    ushort* Wout_t  = (ushort*)alloc((size_t)C_ * C_ * 2);
    ushort* Wcomb_t = (ushort*)alloc((size_t)128 * C_ * 2);
    float*  cbias   = (float*)alloc(128 * 4);
    // aliases (lifetimes are disjoint):
    float*  scores   = (float*)fn;   // fn dead after value GEMM
    ushort* attn_out = q;            // q dead after scores GEMM

    prep_weights<<<2688, 256, 0, stream>>>(Wv, Woff, Waw, boff, baw, Wout,
                                           Wv_t, Wout_t, Wcomb_t, cbias);
    ln_kernel<<<(2 * M_) / 4, 256, 0, stream>>>(x, feat, qn_w, qn_b, fn_w, fn_b, q, fn);
    gemm_bf16<0><<<dim3(12, 400), 256, 0, stream>>>(fn, Wv_t, bv, value, nullptr, nullptr, C_);
    gemm_bf16<1><<<dim3(2, 400), 256, 0, stream>>>(q, Wcomb_t, cbias, scores, nullptr, nullptr, 128);
    loc_kernel<<<M_ / 4, 256, 0, stream>>>(scores, refp, samp);
    sample_kernel<<<(M_ * NH_) / 4, 256, 0, stream>>>(value, samp, attn_out);
    gemm_bf16<2><<<dim3(12, 400), 256, 0, stream>>>(attn_out, Wout_t, bout, d_out, x, gamma, C_);
}

// Round 2
// 524.286 us; speedup vs baseline: 1.0564x; 1.0564x over previous
//
#include <hip/hip_runtime.h>
#include <hip/hip_bf16.h>

#define B_  4
#define L_  6400
#define C_  768
#define NH_ 6
#define NP_ 4
#define DH_ 128
#define HW_ 80
#define M_  (B_*L_)   // 25600

using f32x4  = float __attribute__((ext_vector_type(4)));
using bf16x8 = short __attribute__((ext_vector_type(8)));

#define AS1(p) ((const __attribute__((address_space(1))) void*)(p))
#define AS3(p) ((__attribute__((address_space(3))) void*)(p))

__device__ __forceinline__ ushort f2bf(float f) {
    __hip_bfloat16 h = __float2bfloat16(f);
    return *reinterpret_cast<ushort*>(&h);
}
__device__ __forceinline__ float bf2f(ushort u) {
    union { unsigned u; float f; } v; v.u = ((unsigned)u) << 16; return v.f;
}

// ---------------- K0: weight prep (transpose + bf16 cast, pad Wcomb to 128 cols)
__global__ __launch_bounds__(256) void prep_weights(
    const float* __restrict__ Wv, const float* __restrict__ Woff,
    const float* __restrict__ Waw, const float* __restrict__ boff,
    const float* __restrict__ baw, const float* __restrict__ Wout,
    ushort* __restrict__ Wv_t, ushort* __restrict__ Wout_t,
    ushort* __restrict__ Wcomb_t, float* __restrict__ comb_bias)
{
    int i = blockIdx.x * 256 + threadIdx.x;
    const int WSZ = C_ * C_;              // 589824
    if (i < WSZ) {
        int n = i / C_, k = i % C_;
        Wv_t[i]   = f2bf(Wv[k * C_ + n]);
        Wout_t[i] = f2bf(Wout[k * C_ + n]);
    } else {
        int j = i - WSZ;
        if (j < 128 * C_) {
            int n = j / C_, k = j % C_;
            float v = 0.f;
            if (n < 48)      v = Woff[k * 48 + n];
            else if (n < 72) v = Waw[k * 24 + (n - 48)];
            Wcomb_t[j] = f2bf(v);
        }
    }
    if (i < 128) {
        float v = 0.f;
        if (i < 48)      v = boff[i];
        else if (i < 72) v = baw[i - 48];
        comb_bias[i] = v;
    }
}

// ---------------- K1: LayerNorm for q (from x) and fnorm (from feat), bf16 out
__global__ __launch_bounds__(256) void ln_kernel(
    const float* __restrict__ x, const float* __restrict__ feat,
    const float* __restrict__ qw, const float* __restrict__ qb,
    const float* __restrict__ fw, const float* __restrict__ fb,
    ushort* __restrict__ q, ushort* __restrict__ fn)
{
    int wave = threadIdx.x >> 6, lane = threadIdx.x & 63;
    long r = (long)blockIdx.x * 4 + wave;          // 0 .. 2*M_-1
    const float* in; ushort* out; const float* w; const float* b;
    if (r < M_) { in = x + r * C_;          out = q  + r * C_;          w = qw; b = qb; }
    else        { long rr = r - M_; in = feat + rr * C_; out = fn + rr * C_; w = fw; b = fb; }

    const float4* in4 = (const float4*)in;
    float4 v[3];
    float s = 0.f, s2 = 0.f;
#pragma unroll
    for (int i = 0; i < 3; i++) {
        v[i] = in4[lane + 64 * i];
        s  += v[i].x + v[i].y + v[i].z + v[i].w;
        s2 += v[i].x*v[i].x + v[i].y*v[i].y + v[i].z*v[i].z + v[i].w*v[i].w;
    }
#pragma unroll
    for (int off = 32; off; off >>= 1) { s += __shfl_xor(s, off); s2 += __shfl_xor(s2, off); }
    float mean = s * (1.f / C_);
    float var  = s2 * (1.f / C_) - mean * mean;
    float rs   = rsqrtf(var + 1e-6f);
#pragma unroll
    for (int i = 0; i < 3; i++) {
        int c = (lane + 64 * i) * 4;
        ushort4 o;
        o.x = f2bf((v[i].x - mean) * rs * w[c + 0] + b[c + 0]);
        o.y = f2bf((v[i].y - mean) * rs * w[c + 1] + b[c + 1]);
        o.z = f2bf((v[i].z - mean) * rs * w[c + 2] + b[c + 2]);
        o.w = f2bf((v[i].w - mean) * rs * w[c + 3] + b[c + 3]);
        ((ushort4*)out)[lane + 64 * i] = o;
    }
}

// ---------------- GEMM (m97 structure): C[M,N] = A[M,K]*Bt[N,K]^T + bias
// 128x128 tile, BK=32, 4 waves each 64x64, global_load_lds staging.
// MODE 0: store bf16 to value_t [B,NH,HW^2,DH]. MODE 1: f32, ldc stride.
// MODE 2: out = xres + gamma * (acc + bias), f32.
template<int MODE>
__global__ __launch_bounds__(256) void gemm_bf16(
    const ushort* __restrict__ A, const ushort* __restrict__ Bt,
    const float* __restrict__ bias, void* __restrict__ Cout,
    const float* __restrict__ xres, const float* __restrict__ gamma,
    int ldc)
{
    const int K = C_;
    __shared__ ushort As[128][32];   // 8 KB, linear (global_load_lds dest)
    __shared__ ushort Bs[128][32];
    const int m0 = blockIdx.y * 128;
    const int n0 = blockIdx.x * 128;
    const int t   = threadIdx.x;
    const int w   = t >> 6, lane = t & 63;
    const int WR = (w >> 1) * 64, WC = (w & 1) * 64;
    const int rowA0 = t >> 2;            // t/4 : 0..63
    const int colA  = (t & 3) * 8;       // k-chunk
    const int row15 = lane & 15, kb = (lane >> 4) * 8;

    f32x4 acc[4][4] = {};
    char* ldsA = (char*)As;
    char* ldsB = (char*)Bs;

    for (int k0 = 0; k0 < K; k0 += 32) {
        __syncthreads();
#pragma unroll
        for (int c = 0; c < 2; c++) {
            const ushort* ga = A  + (long)(m0 + c * 64 + rowA0) * K + k0 + colA;
            const ushort* gb = Bt + (long)(n0 + c * 64 + rowA0) * K + k0 + colA;
            __builtin_amdgcn_global_load_lds(AS1(ga), AS3(ldsA + c * 4096 + w * 1024), 16, 0, 0);
            __builtin_amdgcn_global_load_lds(AS1(gb), AS3(ldsB + c * 4096 + w * 1024), 16, 0, 0);
        }
        __syncthreads();
        bf16x8 af[4], bfr[4];
#pragma unroll
        for (int m = 0; m < 4; m++) af[m]  = *(bf16x8*)&As[WR + m * 16 + row15][kb];
#pragma unroll
        for (int n = 0; n < 4; n++) bfr[n] = *(bf16x8*)&Bs[WC + n * 16 + row15][kb];
#pragma unroll
        for (int m = 0; m < 4; m++)
#pragma unroll
            for (int n = 0; n < 4; n++)
                acc[m][n] = __builtin_amdgcn_mfma_f32_16x16x32_bf16(af[m], bfr[n], acc[m][n], 0, 0, 0);
    }

    const int rbase = (lane >> 4) * 4;
    const int cbase = lane & 15;
    const int bblk = m0 / L_;            // batch index (block-uniform; L_ % 128 == 0)
#pragma unroll
    for (int m = 0; m < 4; m++)
#pragma unroll
    for (int n = 0; n < 4; n++) {
        int gcol = n0 + WC + n * 16 + cbase;
        float bb = bias[gcol];
#pragma unroll
        for (int j = 0; j < 4; j++) {
            int grow = m0 + WR + m * 16 + rbase + j;
            float vv = acc[m][n][j] + bb;
            if (MODE == 0) {
                // value_t[((b*NH + h) * HW^2 + l) * DH + d]
                int l = grow - bblk * L_;
                int h = gcol >> 7, d = gcol & 127;
                long o = (((long)bblk * NH_ + h) * L_ + l) * DH_ + d;
                ((ushort*)Cout)[o] = f2bf(vv);
            } else if (MODE == 1) {
                ((float*)Cout)[(long)grow * ldc + gcol] = vv;
            } else {
                long o = (long)grow * C_ + gcol;
                ((float*)Cout)[o] = xres[o] + gamma[gcol] * vv;
            }
        }
    }
}

// ---------------- K3: per-row softmax over NP=4 per head + sampling locations
__global__ __launch_bounds__(256) void loc_kernel(
    const float* __restrict__ scores,   // [M][128]: 0..47 offs, 48..71 aw logits
    const float* __restrict__ refp,     // [B,L,1,2]
    float4* __restrict__ samp)          // [M][NH*NP] = {lx, ly, w, 0}
{
    int wave = threadIdx.x >> 6, lane = threadIdx.x & 63;
    long row = (long)blockIdx.x * 4 + wave;
    if (lane >= 24) return;
    const float* sc = scores + row * 128;
    int h = lane >> 2, p = lane & 3;
    float ox = sc[h * 8 + p * 2], oy = sc[h * 8 + p * 2 + 1];
    float logit = sc[48 + lane];
    float m = logit;
    m = fmaxf(m, __shfl_xor(m, 1));
    m = fmaxf(m, __shfl_xor(m, 2));
    float e = expf(logit - m);
    float ssum = e;
    ssum += __shfl_xor(ssum, 1);
    ssum += __shfl_xor(ssum, 2);
    float w = e / ssum;
    float rx = refp[row * 2], ry = refp[row * 2 + 1];
    samp[row * 24 + lane] = make_float4(rx * HW_ + ox - 0.5f, ry * HW_ + oy - 0.5f, w, 0.f);
}

// ---------------- K4: bilinear gather + weighted sum -> attn_out (bf16)
// value_t: [B, NH, HW^2, DH]; waves ordered by (b,h,l) for L2 plane locality.
__global__ __launch_bounds__(256) void sample_kernel(
    const ushort* __restrict__ value_t,
    const float4* __restrict__ samp,    // [M][24]
    ushort* __restrict__ attn_out)      // [M][C] bf16
{
    int wave = threadIdx.x >> 6, lane = threadIdx.x & 63;
    int gid = blockIdx.x * 4 + wave;        // (b*NH + h) * L + l
    int bh = gid / L_;  int l = gid - bh * L_;
    int b  = bh / NH_;  int h = bh - b * NH_;
    const ushort* plane = value_t + (long)bh * (HW_ * HW_) * DH_;
    long bl = (long)b * L_ + l;
    const float4* sp = samp + bl * 24 + h * 4;
    float acc0 = 0.f, acc1 = 0.f;
#pragma unroll
    for (int p = 0; p < 4; p++) {
        float4 s = sp[p];
        float lx = s.x, ly = s.y, wgt = s.z;
        float x0f = floorf(lx), y0f = floorf(ly);
        float tx = lx - x0f, ty = ly - y0f;
        int x0 = (int)x0f, y0 = (int)y0f;
#pragma unroll
        for (int dy = 0; dy < 2; dy++) {
            int yi = y0 + dy;
            if (yi < 0 || yi >= HW_) continue;
            float wy = dy ? ty : 1.f - ty;
#pragma unroll
            for (int dx = 0; dx < 2; dx++) {
                int xi = x0 + dx;
                if (xi < 0 || xi >= HW_) continue;
                float wx = dx ? tx : 1.f - tx;
                float wcr = wgt * wy * wx;
                int idx = __builtin_amdgcn_readfirstlane(yi * HW_ + xi);
                unsigned v = *(const unsigned*)(plane + (long)idx * DH_ + lane * 2);
                acc0 += wcr * bf2f((ushort)(v & 0xffffu));
                acc1 += wcr * bf2f((ushort)(v >> 16));
            }
        }
    }
    unsigned o = ((unsigned)f2bf(acc1) << 16) | (unsigned)f2bf(acc0);
    *(unsigned*)(attn_out + bl * C_ + h * DH_ + lane * 2) = o;
}

extern "C" void kernel_launch(void* const* d_in, const int* in_sizes, int n_in,
                              void* d_out, int out_size, void* d_ws, size_t ws_size,
                              hipStream_t stream) {
    const float* x     = (const float*)d_in[0];
    const float* refp  = (const float*)d_in[1];
    const float* feat  = (const float*)d_in[2];
    const float* qn_w  = (const float*)d_in[5];
    const float* qn_b  = (const float*)d_in[6];
    const float* fn_w  = (const float*)d_in[7];
    const float* fn_b  = (const float*)d_in[8];
    const float* gamma = (const float*)d_in[9];
    const float* Wv    = (const float*)d_in[10];
    const float* bv    = (const float*)d_in[11];
    const float* Woff  = (const float*)d_in[12];
    const float* boff  = (const float*)d_in[13];
    const float* Waw   = (const float*)d_in[14];
    const float* baw   = (const float*)d_in[15];
    const float* Wout  = (const float*)d_in[16];
    const float* bout  = (const float*)d_in[17];

    char* ws = (char*)d_ws;
    size_t off = 0;
    auto alloc = [&](size_t bytes) -> void* {
        void* p = ws + off; off += (bytes + 255) & ~(size_t)255; return p;
    };
    ushort* q       = (ushort*)alloc((size_t)M_ * C_ * 2);
    ushort* fn      = (ushort*)alloc((size_t)M_ * C_ * 2);
    ushort* value_t = (ushort*)alloc((size_t)M_ * C_ * 2);
    float4* samp    = (float4*)alloc((size_t)M_ * 24 * 16);
    ushort* Wv_t    = (ushort*)alloc((size_t)C_ * C_ * 2);
    ushort* Wout_t  = (ushort*)alloc((size_t)C_ * C_ * 2);
    ushort* Wcomb_t = (ushort*)alloc((size_t)128 * C_ * 2);
    float*  cbias   = (float*)alloc(128 * 4);
    // aliases (lifetimes are disjoint):
    float*  scores   = (float*)fn;   // fn dead after value GEMM
    ushort* attn_out = q;            // q dead after scores GEMM

    prep_weights<<<2688, 256, 0, stream>>>(Wv, Woff, Waw, boff, baw, Wout,
                                           Wv_t, Wout_t, Wcomb_t, cbias);
    ln_kernel<<<(2 * M_) / 4, 256, 0, stream>>>(x, feat, qn_w, qn_b, fn_w, fn_b, q, fn);
    gemm_bf16<0><<<dim3(6, 200), 256, 0, stream>>>(fn, Wv_t, bv, value_t, nullptr, nullptr, C_);
    gemm_bf16<1><<<dim3(1, 200), 256, 0, stream>>>(q, Wcomb_t, cbias, scores, nullptr, nullptr, 128);
    loc_kernel<<<M_ / 4, 256, 0, stream>>>(scores, refp, samp);
    sample_kernel<<<(M_ * NH_) / 4, 256, 0, stream>>>(value_t, samp, attn_out);
    gemm_bf16<2><<<dim3(6, 200), 256, 0, stream>>>(attn_out, Wout_t, bout, d_out, x, gamma, C_);
}

// Round 4
// 433.438 us; speedup vs baseline: 1.2778x; 1.2096x over previous
//
#include <hip/hip_runtime.h>
#include <hip/hip_bf16.h>

#define B_  4
#define L_  6400
#define C_  768
#define NH_ 6
#define NP_ 4
#define DH_ 128
#define HW_ 80
#define M_  (B_*L_)   // 25600

using f32x4  = float __attribute__((ext_vector_type(4)));
using bf16x8 = short __attribute__((ext_vector_type(8)));

#define AS1(p) ((const __attribute__((address_space(1))) void*)(p))
#define AS3(p) ((__attribute__((address_space(3))) void*)(p))

__device__ __forceinline__ ushort f2bf(float f) {
    __hip_bfloat16 h = __float2bfloat16(f);
    return *reinterpret_cast<ushort*>(&h);
}
__device__ __forceinline__ float bf2f(ushort u) {
    union { unsigned u; float f; } v; v.u = ((unsigned)u) << 16; return v.f;
}

// ---------------- K0: weight prep (transpose + bf16 cast, pad Wcomb to 128 cols)
__global__ __launch_bounds__(256) void prep_weights(
    const float* __restrict__ Wv, const float* __restrict__ Woff,
    const float* __restrict__ Waw, const float* __restrict__ boff,
    const float* __restrict__ baw, const float* __restrict__ Wout,
    ushort* __restrict__ Wv_t, ushort* __restrict__ Wout_t,
    ushort* __restrict__ Wcomb_t, float* __restrict__ comb_bias)
{
    int i = blockIdx.x * 256 + threadIdx.x;
    const int WSZ = C_ * C_;              // 589824
    if (i < WSZ) {
        int n = i / C_, k = i % C_;
        Wv_t[i]   = f2bf(Wv[k * C_ + n]);
        Wout_t[i] = f2bf(Wout[k * C_ + n]);
    } else {
        int j = i - WSZ;
        if (j < 128 * C_) {
            int n = j / C_, k = j % C_;
            float v = 0.f;
            if (n < 48)      v = Woff[k * 48 + n];
            else if (n < 72) v = Waw[k * 24 + (n - 48)];
            Wcomb_t[j] = f2bf(v);
        }
    }
    if (i < 128) {
        float v = 0.f;
        if (i < 48)      v = boff[i];
        else if (i < 72) v = baw[i - 48];
        comb_bias[i] = v;
    }
}

// ---------------- K1: LayerNorm for q (from x) and fnorm (from feat), bf16 out
__global__ __launch_bounds__(256) void ln_kernel(
    const float* __restrict__ x, const float* __restrict__ feat,
    const float* __restrict__ qw, const float* __restrict__ qb,
    const float* __restrict__ fw, const float* __restrict__ fb,
    ushort* __restrict__ q, ushort* __restrict__ fn)
{
    int wave = threadIdx.x >> 6, lane = threadIdx.x & 63;
    long r = (long)blockIdx.x * 4 + wave;          // 0 .. 2*M_-1
    const float* in; ushort* out; const float* w; const float* b;
    if (r < M_) { in = x + r * C_;          out = q  + r * C_;          w = qw; b = qb; }
    else        { long rr = r - M_; in = feat + rr * C_; out = fn + rr * C_; w = fw; b = fb; }

    const float4* in4 = (const float4*)in;
    float4 v[3];
    float s = 0.f, s2 = 0.f;
#pragma unroll
    for (int i = 0; i < 3; i++) {
        v[i] = in4[lane + 64 * i];
        s  += v[i].x + v[i].y + v[i].z + v[i].w;
        s2 += v[i].x*v[i].x + v[i].y*v[i].y + v[i].z*v[i].z + v[i].w*v[i].w;
    }
#pragma unroll
    for (int off = 32; off; off >>= 1) { s += __shfl_xor(s, off); s2 += __shfl_xor(s2, off); }
    float mean = s * (1.f / C_);
    float var  = s2 * (1.f / C_) - mean * mean;
    float rs   = rsqrtf(var + 1e-6f);
#pragma unroll
    for (int i = 0; i < 3; i++) {
        int c = (lane + 64 * i) * 4;
        ushort4 o;
        o.x = f2bf((v[i].x - mean) * rs * w[c + 0] + b[c + 0]);
        o.y = f2bf((v[i].y - mean) * rs * w[c + 1] + b[c + 1]);
        o.z = f2bf((v[i].z - mean) * rs * w[c + 2] + b[c + 2]);
        o.w = f2bf((v[i].w - mean) * rs * w[c + 3] + b[c + 3]);
        ((ushort4*)out)[lane + 64 * i] = o;
    }
}

// ---------------- GEMM (m97 structure): C[M,N] = A[M,K]*Bt[N,K]^T + bias
// 128x128 tile, BK=32, 4 waves each 64x64, global_load_lds staging.
// MODE 0: store bf16 to value_t [B,NH,HW^2,DH]. MODE 1: f32, ldc stride.
// MODE 2: out = xres + gamma * (acc + bias), f32.
template<int MODE>
__global__ __launch_bounds__(256) void gemm_bf16(
    const ushort* __restrict__ A, const ushort* __restrict__ Bt,
    const float* __restrict__ bias, void* __restrict__ Cout,
    const float* __restrict__ xres, const float* __restrict__ gamma,
    int ldc)
{
    const int K = C_;
    __shared__ ushort As[128][32];   // 8 KB, linear (global_load_lds dest)
    __shared__ ushort Bs[128][32];
    const int m0 = blockIdx.y * 128;
    const int n0 = blockIdx.x * 128;
    const int t   = threadIdx.x;
    const int w   = t >> 6, lane = t & 63;
    const int WR = (w >> 1) * 64, WC = (w & 1) * 64;
    const int rowA0 = t >> 2;            // t/4 : 0..63
    const int colA  = (t & 3) * 8;       // k-chunk
    const int row15 = lane & 15, kb = (lane >> 4) * 8;

    f32x4 acc[4][4] = {};
    char* ldsA = (char*)As;
    char* ldsB = (char*)Bs;

    for (int k0 = 0; k0 < K; k0 += 32) {
        __syncthreads();
#pragma unroll
        for (int c = 0; c < 2; c++) {
            const ushort* ga = A  + (long)(m0 + c * 64 + rowA0) * K + k0 + colA;
            const ushort* gb = Bt + (long)(n0 + c * 64 + rowA0) * K + k0 + colA;
            __builtin_amdgcn_global_load_lds(AS1(ga), AS3(ldsA + c * 4096 + w * 1024), 16, 0, 0);
            __builtin_amdgcn_global_load_lds(AS1(gb), AS3(ldsB + c * 4096 + w * 1024), 16, 0, 0);
        }
        __syncthreads();
        bf16x8 af[4], bfr[4];
#pragma unroll
        for (int m = 0; m < 4; m++) af[m]  = *(bf16x8*)&As[WR + m * 16 + row15][kb];
#pragma unroll
        for (int n = 0; n < 4; n++) bfr[n] = *(bf16x8*)&Bs[WC + n * 16 + row15][kb];
#pragma unroll
        for (int m = 0; m < 4; m++)
#pragma unroll
            for (int n = 0; n < 4; n++)
                acc[m][n] = __builtin_amdgcn_mfma_f32_16x16x32_bf16(af[m], bfr[n], acc[m][n], 0, 0, 0);
    }

    const int rbase = (lane >> 4) * 4;
    const int cbase = lane & 15;
    const int bblk = m0 / L_;            // batch index (block-uniform; L_ % 128 == 0)
#pragma unroll
    for (int m = 0; m < 4; m++)
#pragma unroll
    for (int n = 0; n < 4; n++) {
        int gcol = n0 + WC + n * 16 + cbase;
        float bb = bias[gcol];
#pragma unroll
        for (int j = 0; j < 4; j++) {
            int grow = m0 + WR + m * 16 + rbase + j;
            float vv = acc[m][n][j] + bb;
            if (MODE == 0) {
                // value_t[((b*NH + h) * HW^2 + l) * DH + d]
                int l = grow - bblk * L_;
                int h = gcol >> 7, d = gcol & 127;
                long o = (((long)bblk * NH_ + h) * L_ + l) * DH_ + d;
                ((ushort*)Cout)[o] = f2bf(vv);
            } else if (MODE == 1) {
                ((float*)Cout)[(long)grow * ldc + gcol] = vv;
            } else {
                long o = (long)grow * C_ + gcol;
                ((float*)Cout)[o] = xres[o] + gamma[gcol] * vv;
            }
        }
    }
}

// ---------------- K3: per-row softmax over NP=4 per head + sampling locations
__global__ __launch_bounds__(256) void loc_kernel(
    const float* __restrict__ scores,   // [M][128]: 0..47 offs, 48..71 aw logits
    const float* __restrict__ refp,     // [B,L,1,2]
    float4* __restrict__ samp)          // [M][NH*NP] = {lx, ly, w, 0}
{
    int wave = threadIdx.x >> 6, lane = threadIdx.x & 63;
    long row = (long)blockIdx.x * 4 + wave;
    if (lane >= 24) return;
    const float* sc = scores + row * 128;
    int h = lane >> 2, p = lane & 3;
    float ox = sc[h * 8 + p * 2], oy = sc[h * 8 + p * 2 + 1];
    float logit = sc[48 + lane];
    float m = logit;
    m = fmaxf(m, __shfl_xor(m, 1));
    m = fmaxf(m, __shfl_xor(m, 2));
    float e = expf(logit - m);
    float ssum = e;
    ssum += __shfl_xor(ssum, 1);
    ssum += __shfl_xor(ssum, 2);
    float w = e / ssum;
    float rx = refp[row * 2], ry = refp[row * 2 + 1];
    samp[row * 24 + lane] = make_float4(rx * HW_ + ox - 0.5f, ry * HW_ + oy - 0.5f, w, 0.f);
}

// ---------------- K4: bilinear gather + weighted sum -> attn_out (bf16)
// value_t: [B, NH, HW^2, DH]. 16 lanes per (l,h): lane d16 covers channels
// d16*8..d16*8+7 via dwordx4 loads. Branchless validity. 16 (l,h) per block.
__global__ __launch_bounds__(256) void sample_kernel(
    const ushort* __restrict__ value_t,
    const float4* __restrict__ samp,    // [M][24]
    ushort* __restrict__ attn_out)      // [M][C] bf16
{
    // XCD-chunk swizzle: 9600 blocks, 8 XCDs, 1200 contiguous chunks each.
    int bid = (int)(blockIdx.x & 7) * 1200 + (int)(blockIdx.x >> 3);
    int t = threadIdx.x;
    int grp = t >> 4;                 // 0..15  : which (l,h) in this block
    int d16 = t & 15;                 // channel group
    int gid = bid * 16 + grp;         // (b*NH + h) * L + l
    int bh = gid / L_;  int l = gid - bh * L_;
    int b  = bh / NH_;  int h = bh - b * NH_;
    const ushort* plane = value_t + (long)bh * (HW_ * HW_) * DH_ + d16 * 8;
    long bl = (long)b * L_ + l;
    const float4* sp = samp + bl * 24 + h * 4;

    float acc[8] = {};
#pragma unroll
    for (int p = 0; p < 4; p++) {
        float4 s = sp[p];
        float lx = s.x, ly = s.y, wgt = s.z;
        float x0f = floorf(lx), y0f = floorf(ly);
        float tx = lx - x0f, ty = ly - y0f;
        int x0 = (int)x0f, y0 = (int)y0f;
#pragma unroll
        for (int dy = 0; dy < 2; dy++) {
            int yi = y0 + dy;
            float wy = dy ? ty : 1.f - ty;
#pragma unroll
            for (int dx = 0; dx < 2; dx++) {
                int xi = x0 + dx;
                float wx = dx ? tx : 1.f - tx;
                bool valid = (xi >= 0) & (xi < HW_) & (yi >= 0) & (yi < HW_);
                float wc = valid ? (wgt * wy * wx) : 0.f;
                int yc = min(max(yi, 0), HW_ - 1);
                int xc = min(max(xi, 0), HW_ - 1);
                uint4 v = *(const uint4*)(plane + (long)(yc * HW_ + xc) * DH_);
                const unsigned* u = (const unsigned*)&v;
#pragma unroll
                for (int i = 0; i < 4; i++) {
                    union { unsigned q; float f; } lo, hi;
                    lo.q = u[i] << 16;
                    hi.q = u[i] & 0xffff0000u;
                    acc[2 * i]     += wc * lo.f;
                    acc[2 * i + 1] += wc * hi.f;
                }
            }
        }
    }
    bf16x8 o;
#pragma unroll
    for (int i = 0; i < 8; i++) o[i] = (short)f2bf(acc[i]);
    *(bf16x8*)(attn_out + bl * C_ + h * DH_ + d16 * 8) = o;
}

extern "C" void kernel_launch(void* const* d_in, const int* in_sizes, int n_in,
                              void* d_out, int out_size, void* d_ws, size_t ws_size,
                              hipStream_t stream) {
    const float* x     = (const float*)d_in[0];
    const float* refp  = (const float*)d_in[1];
    const float* feat  = (const float*)d_in[2];
    const float* qn_w  = (const float*)d_in[5];
    const float* qn_b  = (const float*)d_in[6];
    const float* fn_w  = (const float*)d_in[7];
    const float* fn_b  = (const float*)d_in[8];
    const float* gamma = (const float*)d_in[9];
    const float* Wv    = (const float*)d_in[10];
    const float* bv    = (const float*)d_in[11];
    const float* Woff  = (const float*)d_in[12];
    const float* boff  = (const float*)d_in[13];
    const float* Waw   = (const float*)d_in[14];
    const float* baw   = (const float*)d_in[15];
    const float* Wout  = (const float*)d_in[16];
    const float* bout  = (const float*)d_in[17];

    char* ws = (char*)d_ws;
    size_t off = 0;
    auto alloc = [&](size_t bytes) -> void* {
        void* p = ws + off; off += (bytes + 255) & ~(size_t)255; return p;
    };
    ushort* q       = (ushort*)alloc((size_t)M_ * C_ * 2);
    ushort* fn      = (ushort*)alloc((size_t)M_ * C_ * 2);
    ushort* value_t = (ushort*)alloc((size_t)M_ * C_ * 2);
    float4* samp    = (float4*)alloc((size_t)M_ * 24 * 16);
    ushort* Wv_t    = (ushort*)alloc((size_t)C_ * C_ * 2);
    ushort* Wout_t  = (ushort*)alloc((size_t)C_ * C_ * 2);
    ushort* Wcomb_t = (ushort*)alloc((size_t)128 * C_ * 2);
    float*  cbias   = (float*)alloc(128 * 4);
    // aliases (lifetimes are disjoint):
    float*  scores   = (float*)fn;   // fn dead after value GEMM
    ushort* attn_out = q;            // q dead after scores GEMM

    prep_weights<<<2688, 256, 0, stream>>>(Wv, Woff, Waw, boff, baw, Wout,
                                           Wv_t, Wout_t, Wcomb_t, cbias);
    ln_kernel<<<(2 * M_) / 4, 256, 0, stream>>>(x, feat, qn_w, qn_b, fn_w, fn_b, q, fn);
    gemm_bf16<0><<<dim3(6, 200), 256, 0, stream>>>(fn, Wv_t, bv, value_t, nullptr, nullptr, C_);
    gemm_bf16<1><<<dim3(1, 200), 256, 0, stream>>>(q, Wcomb_t, cbias, scores, nullptr, nullptr, 128);
    loc_kernel<<<M_ / 4, 256, 0, stream>>>(scores, refp, samp);
    sample_kernel<<<(M_ * NH_) / 16, 256, 0, stream>>>(value_t, samp, attn_out);
    gemm_bf16<2><<<dim3(6, 200), 256, 0, stream>>>(attn_out, Wout_t, bout, d_out, x, gamma, C_);
}

// Round 5
// 427.783 us; speedup vs baseline: 1.2947x; 1.0132x over previous
//
#include <hip/hip_runtime.h>
#include <hip/hip_bf16.h>

#define B_  4
#define L_  6400
#define C_  768
#define NH_ 6
#define NP_ 4
#define DH_ 128
#define HW_ 80
#define M_  (B_*L_)   // 25600

using f32x4  = float __attribute__((ext_vector_type(4)));
using bf16x8 = short __attribute__((ext_vector_type(8)));

#define AS1(p) ((const __attribute__((address_space(1))) void*)(p))
#define AS3(p) ((__attribute__((address_space(3))) void*)(p))

__device__ __forceinline__ ushort f2bf(float f) {
    __hip_bfloat16 h = __float2bfloat16(f);
    return *reinterpret_cast<ushort*>(&h);
}
__device__ __forceinline__ float bf2f(ushort u) {
    union { unsigned u; float f; } v; v.u = ((unsigned)u) << 16; return v.f;
}

// ---------------- K0: weight prep (transpose + bf16 cast, pad Wcomb to 128 cols)
__global__ __launch_bounds__(256) void prep_weights(
    const float* __restrict__ Wv, const float* __restrict__ Woff,
    const float* __restrict__ Waw, const float* __restrict__ boff,
    const float* __restrict__ baw, const float* __restrict__ Wout,
    ushort* __restrict__ Wv_t, ushort* __restrict__ Wout_t,
    ushort* __restrict__ Wcomb_t, float* __restrict__ comb_bias)
{
    int i = blockIdx.x * 256 + threadIdx.x;
    const int WSZ = C_ * C_;              // 589824
    if (i < WSZ) {
        int n = i / C_, k = i % C_;
        Wv_t[i]   = f2bf(Wv[k * C_ + n]);
        Wout_t[i] = f2bf(Wout[k * C_ + n]);
    } else {
        int j = i - WSZ;
        if (j < 128 * C_) {
            int n = j / C_, k = j % C_;
            float v = 0.f;
            if (n < 48)      v = Woff[k * 48 + n];
            else if (n < 72) v = Waw[k * 24 + (n - 48)];
            Wcomb_t[j] = f2bf(v);
        }
    }
    if (i < 128) {
        float v = 0.f;
        if (i < 48)      v = boff[i];
        else if (i < 72) v = baw[i - 48];
        comb_bias[i] = v;
    }
}

// ---------------- K1: LayerNorm for q (from x) and fnorm (from feat), bf16 out
__global__ __launch_bounds__(256) void ln_kernel(
    const float* __restrict__ x, const float* __restrict__ feat,
    const float* __restrict__ qw, const float* __restrict__ qb,
    const float* __restrict__ fw, const float* __restrict__ fb,
    ushort* __restrict__ q, ushort* __restrict__ fn)
{
    int wave = threadIdx.x >> 6, lane = threadIdx.x & 63;
    long r = (long)blockIdx.x * 4 + wave;          // 0 .. 2*M_-1
    const float* in; ushort* out; const float* w; const float* b;
    if (r < M_) { in = x + r * C_;          out = q  + r * C_;          w = qw; b = qb; }
    else        { long rr = r - M_; in = feat + rr * C_; out = fn + rr * C_; w = fw; b = fb; }

    const float4* in4 = (const float4*)in;
    float4 v[3];
    float s = 0.f, s2 = 0.f;
#pragma unroll
    for (int i = 0; i < 3; i++) {
        v[i] = in4[lane + 64 * i];
        s  += v[i].x + v[i].y + v[i].z + v[i].w;
        s2 += v[i].x*v[i].x + v[i].y*v[i].y + v[i].z*v[i].z + v[i].w*v[i].w;
    }
#pragma unroll
    for (int off = 32; off; off >>= 1) { s += __shfl_xor(s, off); s2 += __shfl_xor(s2, off); }
    float mean = s * (1.f / C_);
    float var  = s2 * (1.f / C_) - mean * mean;
    float rs   = rsqrtf(var + 1e-6f);
#pragma unroll
    for (int i = 0; i < 3; i++) {
        int c = (lane + 64 * i) * 4;
        ushort4 o;
        o.x = f2bf((v[i].x - mean) * rs * w[c + 0] + b[c + 0]);
        o.y = f2bf((v[i].y - mean) * rs * w[c + 1] + b[c + 1]);
        o.z = f2bf((v[i].z - mean) * rs * w[c + 2] + b[c + 2]);
        o.w = f2bf((v[i].w - mean) * rs * w[c + 3] + b[c + 3]);
        ((ushort4*)out)[lane + 64 * i] = o;
    }
}

// ---------------- GEMM: C[M,N] = A[M,K]*Bt[N,K]^T + bias, K=768
// 128x128 tile, BK=32, 4 waves each 64x64. T3 minimum-2-phase prefetch
// double-buffer (stage next tile before computing current; ONE barrier/step),
// XCD-bijective block swizzle (grid.x % 8 == 0).
// MODE 0: bf16 to value_t [B,NH,HW^2,DH]. MODE 1: f32, ldc stride.
// MODE 2: out = xres + gamma * (acc + bias), f32.
template<int MODE>
__global__ __launch_bounds__(256) void gemm_bf16(
    const ushort* __restrict__ A, const ushort* __restrict__ Bt,
    const float* __restrict__ bias, void* __restrict__ Cout,
    const float* __restrict__ xres, const float* __restrict__ gamma,
    int ldc, int nbx)
{
    const int K = C_, BK = 32, NT = K / BK;   // 24 K-steps
    __shared__ ushort As[2][128][32];   // 16 KB (two buffers)
    __shared__ ushort Bs[2][128][32];
    // XCD-bijective swizzle: each XCD gets a contiguous chunk of block ids.
    const int nwg = gridDim.x;          // multiple of 8
    const int per = nwg >> 3;
    const int bid = (int)blockIdx.x;
    const int swz = (bid & 7) * per + (bid >> 3);
    const int by = swz / nbx, bx = swz - by * nbx;
    const int m0 = by * 128;
    const int n0 = bx * 128;
    const int t   = threadIdx.x;
    const int w   = t >> 6, lane = t & 63;
    const int WR = (w >> 1) * 64, WC = (w & 1) * 64;
    const int rowA0 = t >> 2;            // 0..63
    const int colA  = (t & 3) * 8;       // k-chunk
    const int row15 = lane & 15, kb = (lane >> 4) * 8;

    f32x4 acc[4][4] = {};

    auto STAGE = [&](int buf, int k0) {
#pragma unroll
        for (int c = 0; c < 2; c++) {
            const ushort* ga = A  + (long)(m0 + c * 64 + rowA0) * K + k0 + colA;
            const ushort* gb = Bt + (long)(n0 + c * 64 + rowA0) * K + k0 + colA;
            __builtin_amdgcn_global_load_lds(AS1(ga), AS3((char*)As + buf * 8192 + c * 4096 + w * 1024), 16, 0, 0);
            __builtin_amdgcn_global_load_lds(AS1(gb), AS3((char*)Bs + buf * 8192 + c * 4096 + w * 1024), 16, 0, 0);
        }
    };
    auto COMPUTE = [&](int buf) {
        bf16x8 af[4], bfr[4];
#pragma unroll
        for (int m = 0; m < 4; m++) af[m]  = *(bf16x8*)&As[buf][WR + m * 16 + row15][kb];
#pragma unroll
        for (int n = 0; n < 4; n++) bfr[n] = *(bf16x8*)&Bs[buf][WC + n * 16 + row15][kb];
#pragma unroll
        for (int m = 0; m < 4; m++)
#pragma unroll
            for (int n = 0; n < 4; n++)
                acc[m][n] = __builtin_amdgcn_mfma_f32_16x16x32_bf16(af[m], bfr[n], acc[m][n], 0, 0, 0);
    };

    STAGE(0, 0);
    __syncthreads();                       // vmcnt(0) drain + barrier
    for (int kt = 0; kt < NT; kt += 2) {
        STAGE(1, (kt + 1) * BK);           // prefetch next while computing cur
        COMPUTE(0);
        __syncthreads();
        if (kt + 2 < NT) STAGE(0, (kt + 2) * BK);
        COMPUTE(1);
        __syncthreads();
    }

    const int rbase = (lane >> 4) * 4;
    const int cbase = lane & 15;
    const int bblk = m0 / L_;            // batch index (block-uniform; L_ % 128 == 0)
#pragma unroll
    for (int m = 0; m < 4; m++)
#pragma unroll
    for (int n = 0; n < 4; n++) {
        int gcol = n0 + WC + n * 16 + cbase;
        float bb = bias[gcol];
#pragma unroll
        for (int j = 0; j < 4; j++) {
            int grow = m0 + WR + m * 16 + rbase + j;
            float vv = acc[m][n][j] + bb;
            if (MODE == 0) {
                // value_t[((b*NH + h) * HW^2 + l) * DH + d]
                int l = grow - bblk * L_;
                int h = gcol >> 7, d = gcol & 127;
                long o = (((long)bblk * NH_ + h) * L_ + l) * DH_ + d;
                ((ushort*)Cout)[o] = f2bf(vv);
            } else if (MODE == 1) {
                ((float*)Cout)[(long)grow * ldc + gcol] = vv;
            } else {
                long o = (long)grow * C_ + gcol;
                ((float*)Cout)[o] = xres[o] + gamma[gcol] * vv;
            }
        }
    }
}

// ---------------- K3: per-row softmax over NP=4 per head + sampling locations
__global__ __launch_bounds__(256) void loc_kernel(
    const float* __restrict__ scores,   // [M][128]: 0..47 offs, 48..71 aw logits
    const float* __restrict__ refp,     // [B,L,1,2]
    float4* __restrict__ samp)          // [M][NH*NP] = {lx, ly, w, 0}
{
    int wave = threadIdx.x >> 6, lane = threadIdx.x & 63;
    long row = (long)blockIdx.x * 4 + wave;
    if (lane >= 24) return;
    const float* sc = scores + row * 128;
    int h = lane >> 2, p = lane & 3;
    float ox = sc[h * 8 + p * 2], oy = sc[h * 8 + p * 2 + 1];
    float logit = sc[48 + lane];
    float m = logit;
    m = fmaxf(m, __shfl_xor(m, 1));
    m = fmaxf(m, __shfl_xor(m, 2));
    float e = expf(logit - m);
    float ssum = e;
    ssum += __shfl_xor(ssum, 1);
    ssum += __shfl_xor(ssum, 2);
    float w = e / ssum;
    float rx = refp[row * 2], ry = refp[row * 2 + 1];
    samp[row * 24 + lane] = make_float4(rx * HW_ + ox - 0.5f, ry * HW_ + oy - 0.5f, w, 0.f);
}

// ---------------- K4: bilinear gather + weighted sum -> attn_out (bf16)
// value_t: [B, NH, HW^2, DH]. 16 lanes per (l,h): lane d16 covers channels
// d16*8..d16*8+7 via dwordx4 loads. Branchless validity. 16 (l,h) per block.
__global__ __launch_bounds__(256) void sample_kernel(
    const ushort* __restrict__ value_t,
    const float4* __restrict__ samp,    // [M][24]
    ushort* __restrict__ attn_out)      // [M][C] bf16
{
    // XCD-chunk swizzle: 9600 blocks, 8 XCDs, 1200 contiguous chunks each.
    int bid = (int)(blockIdx.x & 7) * 1200 + (int)(blockIdx.x >> 3);
    int t = threadIdx.x;
    int grp = t >> 4;                 // 0..15  : which (l,h) in this block
    int d16 = t & 15;                 // channel group
    int gid = bid * 16 + grp;         // (b*NH + h) * L + l
    int bh = gid / L_;  int l = gid - bh * L_;
    int b  = bh / NH_;  int h = bh - b * NH_;
    const ushort* plane = value_t + (long)bh * (HW_ * HW_) * DH_ + d16 * 8;
    long bl = (long)b * L_ + l;
    const float4* sp = samp + bl * 24 + h * 4;

    float acc[8] = {};
#pragma unroll
    for (int p = 0; p < 4; p++) {
        float4 s = sp[p];
        float lx = s.x, ly = s.y, wgt = s.z;
        float x0f = floorf(lx), y0f = floorf(ly);
        float tx = lx - x0f, ty = ly - y0f;
        int x0 = (int)x0f, y0 = (int)y0f;
#pragma unroll
        for (int dy = 0; dy < 2; dy++) {
            int yi = y0 + dy;
            float wy = dy ? ty : 1.f - ty;
#pragma unroll
            for (int dx = 0; dx < 2; dx++) {
                int xi = x0 + dx;
                float wx = dx ? tx : 1.f - tx;
                bool valid = (xi >= 0) & (xi < HW_) & (yi >= 0) & (yi < HW_);
                float wc = valid ? (wgt * wy * wx) : 0.f;
                int yc = min(max(yi, 0), HW_ - 1);
                int xc = min(max(xi, 0), HW_ - 1);
                uint4 v = *(const uint4*)(plane + (long)(yc * HW_ + xc) * DH_);
                const unsigned* u = (const unsigned*)&v;
#pragma unroll
                for (int i = 0; i < 4; i++) {
                    union { unsigned q; float f; } lo, hi;
                    lo.q = u[i] << 16;
                    hi.q = u[i] & 0xffff0000u;
                    acc[2 * i]     += wc * lo.f;
                    acc[2 * i + 1] += wc * hi.f;
                }
            }
        }
    }
    bf16x8 o;
#pragma unroll
    for (int i = 0; i < 8; i++) o[i] = (short)f2bf(acc[i]);
    *(bf16x8*)(attn_out + bl * C_ + h * DH_ + d16 * 8) = o;
}

extern "C" void kernel_launch(void* const* d_in, const int* in_sizes, int n_in,
                              void* d_out, int out_size, void* d_ws, size_t ws_size,
                              hipStream_t stream) {
    const float* x     = (const float*)d_in[0];
    const float* refp  = (const float*)d_in[1];
    const float* feat  = (const float*)d_in[2];
    const float* qn_w  = (const float*)d_in[5];
    const float* qn_b  = (const float*)d_in[6];
    const float* fn_w  = (const float*)d_in[7];
    const float* fn_b  = (const float*)d_in[8];
    const float* gamma = (const float*)d_in[9];
    const float* Wv    = (const float*)d_in[10];
    const float* bv    = (const float*)d_in[11];
    const float* Woff  = (const float*)d_in[12];
    const float* boff  = (const float*)d_in[13];
    const float* Waw   = (const float*)d_in[14];
    const float* baw   = (const float*)d_in[15];
    const float* Wout  = (const float*)d_in[16];
    const float* bout  = (const float*)d_in[17];

    char* ws = (char*)d_ws;
    size_t off = 0;
    auto alloc = [&](size_t bytes) -> void* {
        void* p = ws + off; off += (bytes + 255) & ~(size_t)255; return p;
    };
    ushort* q       = (ushort*)alloc((size_t)M_ * C_ * 2);
    ushort* fn      = (ushort*)alloc((size_t)M_ * C_ * 2);
    ushort* value_t = (ushort*)alloc((size_t)M_ * C_ * 2);
    float4* samp    = (float4*)alloc((size_t)M_ * 24 * 16);
    ushort* Wv_t    = (ushort*)alloc((size_t)C_ * C_ * 2);
    ushort* Wout_t  = (ushort*)alloc((size_t)C_ * C_ * 2);
    ushort* Wcomb_t = (ushort*)alloc((size_t)128 * C_ * 2);
    float*  cbias   = (float*)alloc(128 * 4);
    // aliases (lifetimes are disjoint):
    float*  scores   = (float*)fn;   // fn dead after value GEMM
    ushort* attn_out = q;            // q dead after scores GEMM

    prep_weights<<<2688, 256, 0, stream>>>(Wv, Woff, Waw, boff, baw, Wout,
                                           Wv_t, Wout_t, Wcomb_t, cbias);
    ln_kernel<<<(2 * M_) / 4, 256, 0, stream>>>(x, feat, qn_w, qn_b, fn_w, fn_b, q, fn);
    gemm_bf16<0><<<1200, 256, 0, stream>>>(fn, Wv_t, bv, value_t, nullptr, nullptr, C_, 6);
    gemm_bf16<1><<<200, 256, 0, stream>>>(q, Wcomb_t, cbias, scores, nullptr, nullptr, 128, 1);
    loc_kernel<<<M_ / 4, 256, 0, stream>>>(scores, refp, samp);
    sample_kernel<<<(M_ * NH_) / 16, 256, 0, stream>>>(value_t, samp, attn_out);
    gemm_bf16<2><<<1200, 256, 0, stream>>>(attn_out, Wout_t, bout, d_out, x, gamma, C_, 6);
}